// Round 19
// baseline (82.663 us; speedup 1.0000x reference)
//
#include <hip/hip_runtime.h>
#include <cstddef>

#define B_   4
#define NQ_  8192
#define C_   256
#define H_   128
#define W_   128
#define HW_  (H_ * W_)
#define NH_  8
#define NP_  4
#define HD_  32

typedef __attribute__((ext_vector_type(8))) short s16x8;
typedef __attribute__((ext_vector_type(4))) float f32x4;

__device__ __forceinline__ short f2bf(float x) {
    unsigned u = __float_as_uint(x);
    unsigned r = (u + 0x7FFFu + ((u >> 16) & 1u)) >> 16;
    return (short)r;
}
__device__ __forceinline__ unsigned cvt_pk_bf16(float lo, float hi) {
    unsigned r;
    asm("v_cvt_pk_bf16_f32 %0, %1, %2" : "=v"(r) : "v"(lo), "v"(hi));
    return r;
}
__device__ __forceinline__ void gload_lds16(const void* g, void* l) {
    __builtin_amdgcn_global_load_lds(
        (const __attribute__((address_space(1))) void*)g,
        (__attribute__((address_space(3))) void*)l, 16, 0, 0);
}

#define SCHED0 __builtin_amdgcn_sched_barrier(0)
#define VMW2 do { SCHED0; asm volatile("s_waitcnt vmcnt(2)" ::: "memory"); SCHED0; } while (0)
#define VMW0 do { SCHED0; asm volatile("s_waitcnt vmcnt(0)" ::: "memory"); SCHED0; } while (0)
#define LGKM0 do { asm volatile("s_waitcnt lgkmcnt(0)" ::: "memory"); } while (0)

// ---------------------------------------------------------------------------
// Prep: transposed bf16 weights Bt[n][k]. BtOA padded to 256 rows (rows
// 96..255 zero; pgemm-half uses rows 0..127).
// ---------------------------------------------------------------------------
__global__ void prep_kernel(const float* __restrict__ Wv, const float* __restrict__ Wo,
                            const float* __restrict__ Woff, const float* __restrict__ Wattn,
                            const float* __restrict__ boff, const float* __restrict__ battn,
                            short* __restrict__ BtVal, short* __restrict__ BtOut,
                            short* __restrict__ BtOA, float* __restrict__ biasOA)
{
    const int b = blockIdx.x, t = threadIdx.x;   // t = k index, 0..255
    if (b < 256) {
        const int n = b;
        BtVal[(size_t)n * 256 + t] = f2bf(Wv[(size_t)t * 256 + n]);
    } else if (b < 512) {
        const int n = b - 256;
        BtOut[(size_t)n * 256 + t] = f2bf(Wo[(size_t)t * 256 + n]);
    } else {
        const int n = b - 512;   // 0..255
        float v = (n < 64) ? Woff[(size_t)t * 64 + n]
                           : (n < 96 ? Wattn[(size_t)t * 32 + (n - 64)] : 0.f);
        BtOA[(size_t)n * 256 + t] = f2bf(v);
        if (t == 0) biasOA[n] = (n < 64) ? boff[n] : (n < 96 ? battn[n - 64] : 0.f);
    }
}

// ---------------------------------------------------------------------------
// Persistent B-stationary GEMM, SPLIT-N HALF-PANEL, 2 blocks/CU.
// 512 blocks x 512 threads (8 waves = 2wm x 4wn of 64m x 32n; acc[4][2]).
// LDS = B half-panel 64 KB (128 n x 256 k, XOR-swizzled seg ^= row&15 via
// pre-swizzled gload source) + A dbuf 2 x 8 KB UNPADDED = exactly 80 KB
// -> 2 blocks/CU = two INDEPENDENT barrier groups that hide each other's
// VMW stalls (the 1-block/CU lockstep was the R10-R17 plateau's residual).
// Inner loop protocol identical to R13 (2-deep reg prefetch, counted VMW2,
// cvt_pk, one barrier/step) + T5 setprio around the MFMA cluster (R18 +2.2us).
// Even bid -> n-half 0: 2 K1 chunks + restage BtOA + 1 K2a chunk (real 128
// cols only - no more zero-pad compute). Odd bid -> n-half 1: 2 K1 chunks.
// A fetched twice (once per half) - HBM had 65% headroom.
// ---------------------------------------------------------------------------
__device__ __forceinline__ void stage_B_half(const short* __restrict__ BtRows,
                                             short* Bsm, int tid)
{
    const int w = tid >> 6;
#pragma unroll
    for (int j = 0; j < 8; ++j) {
        const int row = j * 16 + (tid >> 5);
        const int src = (tid & 31) ^ (row & 15);        // pre-swizzled source
        gload_lds16(&BtRows[(size_t)row * 256 + src * 8],
                    (char*)Bsm + j * 8192 + w * 1024);
    }
}

template<int OM>   // 2 = vproj permute store (bf16), 0 = oa store n<96 (f32)
__device__ __forceinline__ void do_chunk_h(
    const float* __restrict__ Af, int m0, int nhalf,
    const float* __restrict__ biasH, void* __restrict__ Cp,
    const short* Bsm, char* As64, int tid, int l, int wm, int wn)
{
    const int arow = tid >> 2, aseg = tid & 3;          // A staging map
    const int frag_r = l & 15;
    const int g = l >> 4;                               // k seg within step

    float4 pend[2][2];
#define ISSUE(kk, slot)                                                       \
    { const float4* p_ = (const float4*)(Af + (size_t)(m0 + arow) * 256       \
                                         + (kk) * 32 + aseg * 8);             \
      pend[slot][0] = p_[0]; pend[slot][1] = p_[1]; }
#define CVTW(slot, buf)                                                       \
    { union { unsigned u[4]; s16x8 v; } pk_;                                  \
      pk_.u[0] = cvt_pk_bf16(pend[slot][0].x, pend[slot][0].y);               \
      pk_.u[1] = cvt_pk_bf16(pend[slot][0].z, pend[slot][0].w);               \
      pk_.u[2] = cvt_pk_bf16(pend[slot][1].x, pend[slot][1].y);               \
      pk_.u[3] = cvt_pk_bf16(pend[slot][1].z, pend[slot][1].w);               \
      *(s16x8*)(As64 + (buf) * 8192 + arow * 64 + aseg * 16) = pk_.v; }

    f32x4 acc[4][2];
#pragma unroll
    for (int i = 0; i < 4; ++i)
#pragma unroll
        for (int j = 0; j < 2; ++j) acc[i][j] = (f32x4)0.f;

    // prologue: 2-deep A prefetch (VMW2 also drains this wave's B-stage;
    // barrier then guarantees every wave's stage landed - R13-proven entry)
    ISSUE(0, 0); ISSUE(1, 1); SCHED0;
    VMW2;
    CVTW(0, 0); LGKM0;
    __builtin_amdgcn_s_barrier();

#pragma unroll
    for (int k = 0; k < 8; ++k) {
        if (k <= 5) { ISSUE(k + 2, k & 1); SCHED0; }
        // ---- compute step k from buf[k&1] + Bsm ----
        s16x8 a[4], b[2];
#pragma unroll
        for (int mf = 0; mf < 4; ++mf) {
            const int row = wm * 64 + mf * 16 + frag_r;
            a[mf] = *(const s16x8*)(As64 + (k & 1) * 8192 + row * 64 + g * 16);
        }
#pragma unroll
        for (int nf = 0; nf < 2; ++nf) {
            const int brow = wn * 32 + nf * 16 + frag_r;
            const int phys = (k * 4 + g) ^ (brow & 15);
            b[nf] = *(const s16x8*)((const char*)Bsm + brow * 512 + phys * 16);
        }
        __builtin_amdgcn_s_setprio(1);   // T5 (R18-proven)
#pragma unroll
        for (int mf = 0; mf < 4; ++mf)
#pragma unroll
            for (int nf = 0; nf < 2; ++nf)
                acc[mf][nf] = __builtin_amdgcn_mfma_f32_16x16x32_bf16(
                    a[mf], b[nf], acc[mf][nf], 0, 0, 0);
        __builtin_amdgcn_s_setprio(0);
        // ---- land step k+1, write its buffer, one barrier ----
        if (k < 7) {
            if (k <= 5) { VMW2; } else { VMW0; }
            CVTW((k + 1) & 1, (k + 1) & 1);
            LGKM0;
            __builtin_amdgcn_s_barrier();
        }
    }
#undef ISSUE
#undef CVTW

    // ---- epilogue: C frag layout col=lane&15, row=(lane>>4)*4+reg ----
    const int col_local = wn * 32 + (l & 15);
    const int rbase = wm * 64 + (l >> 4) * 4;
#pragma unroll
    for (int nf = 0; nf < 2; ++nf) {
        const int nloc = col_local + nf * 16;            // 0..127
        if (OM == 0 && nloc >= 96) continue;
        const float bs = biasH[nloc];
#pragma unroll
        for (int mf = 0; mf < 4; ++mf) {
            const f32x4 v = acc[mf][nf];
#pragma unroll
            for (int rr = 0; rr < 4; ++rr) {
                const int m = m0 + rbase + mf * 16 + rr;
                const float o = v[rr] + bs;
                if (OM == 0) {
                    ((float*)Cp)[(size_t)m * 128 + nloc] = o;
                } else {
                    const int n = nhalf * 128 + nloc;
                    const int bb = m >> 14, pix = m & (HW_ - 1);
                    const int h = n >> 5, d = n & 31;
                    ((short*)Cp)[((size_t)(bb * NH_ + h) * HW_ + pix) * HD_ + d] = f2bf(o);
                }
            }
        }
    }
}

__global__ __launch_bounds__(512, 2)
void pgemm(const float* __restrict__ value, const short* __restrict__ BtVal,
           const float* __restrict__ b_val, short* __restrict__ vproj,
           const float* __restrict__ query, const short* __restrict__ BtOA,
           const float* __restrict__ biasOA, float* __restrict__ oa)
{
    __shared__ __align__(16) short Bsm[128 * 256];      // 64 KB half-panel
    __shared__ __align__(16) char  As64[2 * 8192];      // 16 KB unpadded dbuf
    const int tid = threadIdx.x;
    const int l = tid & 63;
    const int w = tid >> 6;
    const int wm = w >> 2, wn = w & 3;
    const int bid = blockIdx.x;                          // 0..511, 2 blocks/CU
    const int half = bid & 1;
    const int mc = bid >> 1;                             // 0..255

    stage_B_half(BtVal + (size_t)half * 128 * 256, Bsm, tid);
    // do_chunk_h prologue VMW2 + s_barrier = stage drain/sync (R13 protocol)

    // K1: two 128-row chunks of value at this n-half
    do_chunk_h<2>(value, mc * 128, half, b_val + half * 128, vproj,
                  Bsm, As64, tid, l, wm, wn);
    do_chunk_h<2>(value, (mc + 256) * 128, half, b_val + half * 128, vproj,
                  Bsm, As64, tid, l, wm, wn);

    if (half == 0) {
        // K2a (cols 0..95 live in half 0): restage BtOA rows 0..127
        __syncthreads();                                 // all reads of BtVal done
        stage_B_half(BtOA, Bsm, tid);
        do_chunk_h<0>(query, mc * 128, 0, biasOA, oa, Bsm, As64, tid, l, wm, wn);
    }
}

// ---------------------------------------------------------------------------
// K3: out = samp @ W_out + b_out. R6-proven path (A bf16, 2-phase dbuf,
// 4 waves, 128x128 tile, all staging via global_load_lds) + T5 setprio.
// Grid 512.
// ---------------------------------------------------------------------------
__global__ __launch_bounds__(256, 4)
void gemm_k3(const short* __restrict__ A16, const short* __restrict__ Bt,
             const float* __restrict__ bias, float* __restrict__ Cp)
{
    __shared__ char  AsRaw[2 * 8192];
    __shared__ short Bs[2 * 4096];
    const int tid = threadIdx.x;
    const int l = tid & 63;
    const int w = tid >> 6;
    const int wm = w >> 1, wn = w & 1;
    const int m0 = (blockIdx.x >> 1) * 128;
    const int n0 = (blockIdx.x & 1) * 128;

    f32x4 acc[4][4];
#pragma unroll
    for (int i = 0; i < 4; ++i)
#pragma unroll
        for (int j = 0; j < 4; ++j) acc[i][j] = (f32x4)0.f;

    const int frag_r = l & 15;
    const int kslot  = (l >> 4) * 8;

#define STAGE_B3(k0, buf)                                                     \
    _Pragma("unroll")                                                         \
    for (int r = 0; r < 2; ++r) {                                             \
        const int i = r * 256 + tid;                                          \
        gload_lds16(&Bt[(size_t)(n0 + (i >> 2)) * 256 + (k0) + (i & 3) * 8],  \
                    (char*)Bs + (buf) * 8192 + r * 4096 + w * 1024);          \
    }
#define STAGE_A3(k0, buf)                                                     \
    _Pragma("unroll")                                                         \
    for (int r = 0; r < 2; ++r) {                                             \
        const int i = r * 256 + tid;                                          \
        gload_lds16(&A16[(size_t)(m0 + (i >> 2)) * 256 + (k0) + (i & 3) * 8], \
                    AsRaw + (buf) * 8192 + r * 4096 + w * 1024);              \
    }

    STAGE_B3(0, 0);
    STAGE_A3(0, 0);
    __syncthreads();

#pragma unroll
    for (int k = 0; k < 8; ++k) {
        const int cur = k & 1, nxt = cur ^ 1;
        if (k < 7) {
            STAGE_B3((k + 1) * 32, nxt);
            STAGE_A3((k + 1) * 32, nxt);
        }
        s16x8 a[4], b[4];
#pragma unroll
        for (int mf = 0; mf < 4; ++mf)
            a[mf] = *(const s16x8*)(AsRaw + cur * 8192 + (wm * 64 + mf * 16 + frag_r) * 64 + kslot * 2);
#pragma unroll
        for (int nf = 0; nf < 4; ++nf)
            b[nf] = *(const s16x8*)&Bs[cur * 4096 + (wn * 64 + nf * 16 + frag_r) * 32 + kslot];
        __builtin_amdgcn_s_setprio(1);
#pragma unroll
        for (int mf = 0; mf < 4; ++mf)
#pragma unroll
            for (int nf = 0; nf < 4; ++nf)
                acc[mf][nf] = __builtin_amdgcn_mfma_f32_16x16x32_bf16(
                    a[mf], b[nf], acc[mf][nf], 0, 0, 0);
        __builtin_amdgcn_s_setprio(0);
        if (k < 7) __syncthreads();
    }
#undef STAGE_A3
#undef STAGE_B3

    const int col_local = wn * 64 + (l & 15);
    const int rbase = wm * 64 + (l >> 4) * 4;
#pragma unroll
    for (int nf = 0; nf < 4; ++nf) {
        const int n = n0 + col_local + nf * 16;
        const float bs = bias[n];
#pragma unroll
        for (int mf = 0; mf < 4; ++mf) {
            const f32x4 v = acc[mf][nf];
#pragma unroll
            for (int rr = 0; rr < 4; ++rr)
                Cp[(size_t)(m0 + rbase + mf * 16 + rr) * 256 + n] = v[rr] + bs;
        }
    }
}

// ---------------------------------------------------------------------------
// Sampling (v2, R10-proven): block = 256 threads = 2 queries. Phase 1
// (tid<64): softmax + corner indices + pre-multiplied weights -> LDS.
// Phase 2: 128 threads/query, thread=(h=t>>4, d0=(t&15)*2), uint gathers.
// ---------------------------------------------------------------------------
__global__ __launch_bounds__(256)
void sample_kernel(const float* __restrict__ oa,    // [B*NQ, 128] (96 used)
                   const float* __restrict__ ref,   // [B*NQ, 2]
                   const short* __restrict__ vproj, // [B*NH, HW, HD] bf16
                   short* __restrict__ samp)        // [B*NQ, 256] bf16
{
    __shared__ int4   s_idx[2][32];
    __shared__ float4 s_w[2][32];
    const int tid = threadIdx.x;
    const int q0 = blockIdx.x * 2;

    if (tid < 64) {
        const int qq = tid >> 5;
        const int hp = tid & 31;
        const int h = hp >> 2, p = hp & 3;
        const int q = q0 + qq;
        const float logit = oa[(size_t)q * 128 + 64 + h * 4 + p];
        float mx = fmaxf(logit, __shfl_xor(logit, 1));
        mx = fmaxf(mx, __shfl_xor(mx, 2));
        float e = __expf(logit - mx);
        float s = e + __shfl_xor(e, 1);
        s += __shfl_xor(s, 2);
        const float aw = e / s;

        const float ox = oa[(size_t)q * 128 + h * 8 + p * 2 + 0] * (0.1f / (float)W_);
        const float oy = oa[(size_t)q * 128 + h * 8 + p * 2 + 1] * (0.1f / (float)H_);
        const float lx = fminf(fmaxf(ref[(size_t)q * 2 + 0] + ox, 0.f), 1.f);
        const float ly = fminf(fmaxf(ref[(size_t)q * 2 + 1] + oy, 0.f), 1.f);
        const float gx = fminf(fmaxf(lx * (float)W_ - 0.5f, 0.f), (float)(W_ - 1));
        const float gy = fminf(fmaxf(ly * (float)H_ - 0.5f, 0.f), (float)(H_ - 1));
        const float x0f = floorf(gx), y0f = floorf(gy);
        const float fx = gx - x0f, fy = gy - y0f;
        const int x0 = (int)x0f, y0 = (int)y0f;
        const int x1 = min(x0 + 1, W_ - 1), y1 = min(y0 + 1, H_ - 1);
        s_idx[qq][hp] = make_int4((y0 * W_ + x0) * HD_, (y0 * W_ + x1) * HD_,
                                  (y1 * W_ + x0) * HD_, (y1 * W_ + x1) * HD_);
        const float gx1 = 1.f - fx, gy1 = 1.f - fy;
        s_w[qq][hp] = make_float4(aw * gx1 * gy1, aw * fx * gy1,
                                  aw * gx1 * fy,  aw * fx * fy);
    }
    __syncthreads();

    const int qq = tid >> 7;
    const int t = tid & 127;
    const int h = t >> 4;
    const int d0 = (t & 15) * 2;
    const int q = q0 + qq;
    const int b = q >> 13;
    const short* vh = vproj + (size_t)(b * NH_ + h) * (HW_ * HD_) + d0;

    float a0 = 0.f, a1 = 0.f;
#pragma unroll
    for (int p = 0; p < 4; ++p) {
        const int4   ii = s_idx[qq][h * 4 + p];
        const float4 ww = s_w[qq][h * 4 + p];
        unsigned v;
        v = *(const unsigned*)&vh[ii.x];
        a0 = fmaf(ww.x, __uint_as_float(v << 16), a0);
        a1 = fmaf(ww.x, __uint_as_float(v & 0xFFFF0000u), a1);
        v = *(const unsigned*)&vh[ii.y];
        a0 = fmaf(ww.y, __uint_as_float(v << 16), a0);
        a1 = fmaf(ww.y, __uint_as_float(v & 0xFFFF0000u), a1);
        v = *(const unsigned*)&vh[ii.z];
        a0 = fmaf(ww.z, __uint_as_float(v << 16), a0);
        a1 = fmaf(ww.z, __uint_as_float(v & 0xFFFF0000u), a1);
        v = *(const unsigned*)&vh[ii.w];
        a0 = fmaf(ww.w, __uint_as_float(v << 16), a0);
        a1 = fmaf(ww.w, __uint_as_float(v & 0xFFFF0000u), a1);
    }
    const unsigned lo = (unsigned)(unsigned short)f2bf(a0);
    const unsigned hi = (unsigned)(unsigned short)f2bf(a1);
    ((unsigned*)samp)[((size_t)q * 256 + h * HD_ + d0) >> 1] = lo | (hi << 16);
}

// ---------------------------------------------------------------------------
extern "C" void kernel_launch(void* const* d_in, const int* in_sizes, int n_in,
                              void* d_out, int out_size, void* d_ws, size_t ws_size,
                              hipStream_t stream)
{
    const float* query  = (const float*)d_in[0];
    const float* refpt  = (const float*)d_in[1];
    const float* value  = (const float*)d_in[2];
    const float* W_off  = (const float*)d_in[3];
    const float* b_off  = (const float*)d_in[4];
    const float* W_attn = (const float*)d_in[5];
    const float* b_attn = (const float*)d_in[6];
    const float* W_val  = (const float*)d_in[7];
    const float* b_val  = (const float*)d_in[8];
    const float* W_out  = (const float*)d_in[9];
    const float* b_out  = (const float*)d_in[10];
    float* out = (float*)d_out;

    char* ws = (char*)d_ws;
    short* vproj  = (short*)ws;                                   // 32 MiB bf16
    short* samp   = (short*)(ws + (size_t)32 * 1024 * 1024);      // 16 MiB bf16
    float* oa     = (float*)(ws + (size_t)48 * 1024 * 1024);      // 16 MiB f32 [32768][128]
    short* BtVal  = (short*)(ws + (size_t)64 * 1024 * 1024);      // 128 KiB
    short* BtOut  = BtVal + 256 * 256;                            // 128 KiB
    short* BtOA   = BtOut + 256 * 256;                            // 128 KiB (256 rows)
    float* biasOA = (float*)(BtOA + 256 * 256);                   // 1 KiB

    prep_kernel<<<768, 256, 0, stream>>>(W_val, W_out, W_off, W_attn,
                                         b_off, b_attn, BtVal, BtOut, BtOA, biasOA);

    // K1 + K2a: persistent half-panel B-stationary GEMM, 2 blocks/CU
    pgemm<<<512, 512, 0, stream>>>(value, BtVal, b_val, vproj,
                                   query, BtOA, biasOA, oa);

    // K2b: bilinear deformable sampling -> samp (bf16), 2 queries/block
    sample_kernel<<<(B_ * NQ_) / 2, 256, 0, stream>>>(oa, refpt, vproj, samp);

    // K3: out = samp @ W_out + b_out, f32
    gemm_k3<<<512, 256, 0, stream>>>(samp, BtOut, b_out, out);
}

// Round 20
// 71.665 us; speedup vs baseline: 1.1535x; 1.1535x over previous
//
#include <hip/hip_runtime.h>
#include <cstddef>

#define B_   4
#define NQ_  8192
#define C_   256
#define H_   128
#define W_   128
#define HW_  (H_ * W_)
#define NH_  8
#define NP_  4
#define HD_  32

typedef __attribute__((ext_vector_type(8))) short s16x8;
typedef __attribute__((ext_vector_type(4))) float f32x4;

__device__ __forceinline__ short f2bf(float x) {
    unsigned u = __float_as_uint(x);
    unsigned r = (u + 0x7FFFu + ((u >> 16) & 1u)) >> 16;
    return (short)r;
}
__device__ __forceinline__ unsigned cvt_pk_bf16(float lo, float hi) {
    unsigned r;
    asm("v_cvt_pk_bf16_f32 %0, %1, %2" : "=v"(r) : "v"(lo), "v"(hi));
    return r;
}
__device__ __forceinline__ void gload_lds16(const void* g, void* l) {
    __builtin_amdgcn_global_load_lds(
        (const __attribute__((address_space(1))) void*)g,
        (__attribute__((address_space(3))) void*)l, 16, 0, 0);
}

#define SCHED0 __builtin_amdgcn_sched_barrier(0)
#define VMW2 do { SCHED0; asm volatile("s_waitcnt vmcnt(2)" ::: "memory"); SCHED0; } while (0)
#define VMW0 do { SCHED0; asm volatile("s_waitcnt vmcnt(0)" ::: "memory"); SCHED0; } while (0)
#define LGKM0 do { asm volatile("s_waitcnt lgkmcnt(0)" ::: "memory"); } while (0)

// ---------------------------------------------------------------------------
// Prep: transposed bf16 weights Bt[n][k]. BtOA padded to 256 rows (rows
// 96..255 zero) so the persistent GEMM uses a uniform N=256 geometry.
// ---------------------------------------------------------------------------
__global__ void prep_kernel(const float* __restrict__ Wv, const float* __restrict__ Wo,
                            const float* __restrict__ Woff, const float* __restrict__ Wattn,
                            const float* __restrict__ boff, const float* __restrict__ battn,
                            short* __restrict__ BtVal, short* __restrict__ BtOut,
                            short* __restrict__ BtOA, float* __restrict__ biasOA)
{
    const int b = blockIdx.x, t = threadIdx.x;   // t = k index, 0..255
    if (b < 256) {
        const int n = b;
        BtVal[(size_t)n * 256 + t] = f2bf(Wv[(size_t)t * 256 + n]);
    } else if (b < 512) {
        const int n = b - 256;
        BtOut[(size_t)n * 256 + t] = f2bf(Wo[(size_t)t * 256 + n]);
    } else {
        const int n = b - 512;   // 0..255
        float v = (n < 64) ? Woff[(size_t)t * 64 + n]
                           : (n < 96 ? Wattn[(size_t)t * 32 + (n - 64)] : 0.f);
        BtOA[(size_t)n * 256 + t] = f2bf(v);
        if (t == 0) biasOA[n] = (n < 64) ? boff[n] : (n < 96 ? battn[n - 64] : 0.f);
    }
}

// ---------------------------------------------------------------------------
// Persistent B-stationary GEMM (R10 inner loop + R13 partition + R18 T5).
// 256 blocks x 512 threads (8 waves, 2wm x 4wn), 1 block/CU. B panel 128 KB
// in LDS (XOR-swizzled seg ^= row&15 via pre-swizzled gload source). Per
// K-step A fp32 -> regs (2-deep rotating prefetch, counted VMW2) -> cvt_pk ->
// 80 B-padded LDS rows. One barrier per step. T5 setprio around MFMA cluster.
// Partition: gidx = bid*3 + j; gidx<512 -> K1 chunk, else K2a chunk.
// 255/256 blocks stage ONE B panel; only block 170 swaps mid-kernel.
// FINAL CONFIG: best measured 71.76 us (R18). Explored-and-rejected: split-N
// 2blk/CU (R19 +11us), whole-chunk prefetch (R16 +4us), 3-deep (R15 null),
// wave-private A (R12 +42us), counted-vmcnt-only (R9 null), dbuf-only (R8).
// ---------------------------------------------------------------------------
__device__ __forceinline__ void stage_B_lds(const short* __restrict__ Bt,
                                            short* Bsm, int tid)
{
    const int w = tid >> 6;
#pragma unroll
    for (int j = 0; j < 16; ++j) {
        const int row = j * 16 + (tid >> 5);
        const int src = (tid & 31) ^ (row & 15);        // pre-swizzled source
        gload_lds16(&Bt[(size_t)row * 256 + src * 8],
                    (char*)Bsm + j * 8192 + w * 1024);
    }
}

template<int OM>   // 2 = vproj permute store (bf16), 0 = oa store n<96 (f32)
__device__ __forceinline__ void do_chunk(
    const float* __restrict__ Af, int m0, const float* __restrict__ bias,
    void* __restrict__ Cp, const short* Bsm, char* As80,
    int tid, int l, int wm, int wn)
{
    const int arow = tid >> 2, aseg = tid & 3;          // A staging map
    const int frag_r = l & 15;
    const int g = l >> 4;                               // k seg within step

    float4 pend[2][2];
#define ISSUE(kk, slot)                                                       \
    { const float4* p_ = (const float4*)(Af + (size_t)(m0 + arow) * 256       \
                                         + (kk) * 32 + aseg * 8);             \
      pend[slot][0] = p_[0]; pend[slot][1] = p_[1]; }
#define CVTW(slot, buf)                                                       \
    { union { unsigned u[4]; s16x8 v; } pk_;                                  \
      pk_.u[0] = cvt_pk_bf16(pend[slot][0].x, pend[slot][0].y);               \
      pk_.u[1] = cvt_pk_bf16(pend[slot][0].z, pend[slot][0].w);               \
      pk_.u[2] = cvt_pk_bf16(pend[slot][1].x, pend[slot][1].y);               \
      pk_.u[3] = cvt_pk_bf16(pend[slot][1].z, pend[slot][1].w);               \
      *(s16x8*)(As80 + (buf) * 10240 + arow * 80 + aseg * 16) = pk_.v; }

    f32x4 acc[4][4];
#pragma unroll
    for (int i = 0; i < 4; ++i)
#pragma unroll
        for (int j = 0; j < 4; ++j) acc[i][j] = (f32x4)0.f;

    // prologue: 2-deep A prefetch (also drains any older B-stage / stores)
    ISSUE(0, 0); ISSUE(1, 1); SCHED0;
    VMW2;                      // L0 (and all older vmem ops) done
    CVTW(0, 0); LGKM0;
    __builtin_amdgcn_s_barrier();

#pragma unroll
    for (int k = 0; k < 8; ++k) {
        if (k <= 5) { ISSUE(k + 2, k & 1); SCHED0; }
        // ---- compute step k from buf[k&1] + Bsm ----
        s16x8 a[4], b[4];
#pragma unroll
        for (int mf = 0; mf < 4; ++mf) {
            const int row = wm * 64 + mf * 16 + frag_r;
            a[mf] = *(const s16x8*)(As80 + (k & 1) * 10240 + row * 80 + g * 16);
        }
#pragma unroll
        for (int nf = 0; nf < 4; ++nf) {
            const int brow = wn * 64 + nf * 16 + frag_r;
            const int phys = (k * 4 + g) ^ (brow & 15);
            b[nf] = *(const s16x8*)((const char*)Bsm + brow * 512 + phys * 16);
        }
        __builtin_amdgcn_s_setprio(1);   // T5: favor MFMA-phase waves
#pragma unroll
        for (int mf = 0; mf < 4; ++mf)
#pragma unroll
            for (int nf = 0; nf < 4; ++nf)
                acc[mf][nf] = __builtin_amdgcn_mfma_f32_16x16x32_bf16(
                    a[mf], b[nf], acc[mf][nf], 0, 0, 0);
        __builtin_amdgcn_s_setprio(0);
        // ---- land step k+1, write its buffer, one barrier ----
        if (k < 7) {
            if (k <= 5) { VMW2; } else { VMW0; }
            CVTW((k + 1) & 1, (k + 1) & 1);
            LGKM0;
            __builtin_amdgcn_s_barrier();
        }
    }
#undef ISSUE
#undef CVTW

    // ---- epilogue: C frag layout col=lane&15, row=(lane>>4)*4+reg ----
    const int col_local = wn * 64 + (l & 15);
    const int rbase = wm * 64 + (l >> 4) * 4;
#pragma unroll
    for (int nf = 0; nf < 4; ++nf) {
        const int n = col_local + nf * 16;
        if (OM == 0 && n >= 96) continue;
        const float bs = bias[n];
#pragma unroll
        for (int mf = 0; mf < 4; ++mf) {
            const f32x4 v = acc[mf][nf];
#pragma unroll
            for (int rr = 0; rr < 4; ++rr) {
                const int m = m0 + rbase + mf * 16 + rr;
                const float o = v[rr] + bs;
                if (OM == 0) {
                    ((float*)Cp)[(size_t)m * 128 + n] = o;
                } else {
                    const int bb = m >> 14, pix = m & (HW_ - 1);
                    const int h = n >> 5, d = n & 31;
                    ((short*)Cp)[((size_t)(bb * NH_ + h) * HW_ + pix) * HD_ + d] = f2bf(o);
                }
            }
        }
    }
}

__global__ __launch_bounds__(512, 2)
void pgemm(const float* __restrict__ value, const short* __restrict__ BtVal,
           const float* __restrict__ b_val, short* __restrict__ vproj,
           const float* __restrict__ query, const short* __restrict__ BtOA,
           const float* __restrict__ biasOA, float* __restrict__ oa)
{
    __shared__ __align__(16) short Bsm[256 * 256];      // 128 KB
    __shared__ __align__(16) char  As80[2 * 10240];     // 20 KB (80 B rows)
    const int tid = threadIdx.x;
    const int l = tid & 63;
    const int w = tid >> 6;
    const int wm = w >> 2, wn = w & 3;
    const int bid = blockIdx.x;                          // 0..255, 1 block/CU

    bool haveVal = (bid * 3 < 512);
    stage_B_lds(haveVal ? BtVal : BtOA, Bsm, tid);
    // do_chunk's prologue VMW2 + s_barrier provides the stage drain/sync.

    for (int j = 0; j < 3; ++j) {
        const int gidx = bid * 3 + j;                    // 0..767, block-uniform
        if (gidx < 512) {
            do_chunk<2>(value, gidx * 128, b_val, vproj, Bsm, As80, tid, l, wm, wn);
        } else {
            if (haveVal) {                               // boundary block only
                __syncthreads();                         // all reads of BtVal done
                stage_B_lds(BtOA, Bsm, tid);
                haveVal = false;
            }
            do_chunk<0>(query, (gidx - 512) * 128, biasOA, oa, Bsm, As80, tid, l, wm, wn);
        }
    }
}

// ---------------------------------------------------------------------------
// K3: out = samp @ W_out + b_out. R6-proven path (A bf16, 2-phase dbuf,
// 4 waves, 128x128 tile, all staging via global_load_lds) + T5 setprio.
// Grid 512.
// ---------------------------------------------------------------------------
__global__ __launch_bounds__(256, 4)
void gemm_k3(const short* __restrict__ A16, const short* __restrict__ Bt,
             const float* __restrict__ bias, float* __restrict__ Cp)
{
    __shared__ char  AsRaw[2 * 8192];
    __shared__ short Bs[2 * 4096];
    const int tid = threadIdx.x;
    const int l = tid & 63;
    const int w = tid >> 6;
    const int wm = w >> 1, wn = w & 1;
    const int m0 = (blockIdx.x >> 1) * 128;
    const int n0 = (blockIdx.x & 1) * 128;

    f32x4 acc[4][4];
#pragma unroll
    for (int i = 0; i < 4; ++i)
#pragma unroll
        for (int j = 0; j < 4; ++j) acc[i][j] = (f32x4)0.f;

    const int frag_r = l & 15;
    const int kslot  = (l >> 4) * 8;

#define STAGE_B3(k0, buf)                                                     \
    _Pragma("unroll")                                                         \
    for (int r = 0; r < 2; ++r) {                                             \
        const int i = r * 256 + tid;                                          \
        gload_lds16(&Bt[(size_t)(n0 + (i >> 2)) * 256 + (k0) + (i & 3) * 8],  \
                    (char*)Bs + (buf) * 8192 + r * 4096 + w * 1024);          \
    }
#define STAGE_A3(k0, buf)                                                     \
    _Pragma("unroll")                                                         \
    for (int r = 0; r < 2; ++r) {                                             \
        const int i = r * 256 + tid;                                          \
        gload_lds16(&A16[(size_t)(m0 + (i >> 2)) * 256 + (k0) + (i & 3) * 8], \
                    AsRaw + (buf) * 8192 + r * 4096 + w * 1024);              \
    }

    STAGE_B3(0, 0);
    STAGE_A3(0, 0);
    __syncthreads();

#pragma unroll
    for (int k = 0; k < 8; ++k) {
        const int cur = k & 1, nxt = cur ^ 1;
        if (k < 7) {
            STAGE_B3((k + 1) * 32, nxt);
            STAGE_A3((k + 1) * 32, nxt);
        }
        s16x8 a[4], b[4];
#pragma unroll
        for (int mf = 0; mf < 4; ++mf)
            a[mf] = *(const s16x8*)(AsRaw + cur * 8192 + (wm * 64 + mf * 16 + frag_r) * 64 + kslot * 2);
#pragma unroll
        for (int nf = 0; nf < 4; ++nf)
            b[nf] = *(const s16x8*)&Bs[cur * 4096 + (wn * 64 + nf * 16 + frag_r) * 32 + kslot];
        __builtin_amdgcn_s_setprio(1);
#pragma unroll
        for (int mf = 0; mf < 4; ++mf)
#pragma unroll
            for (int nf = 0; nf < 4; ++nf)
                acc[mf][nf] = __builtin_amdgcn_mfma_f32_16x16x32_bf16(
                    a[mf], b[nf], acc[mf][nf], 0, 0, 0);
        __builtin_amdgcn_s_setprio(0);
        if (k < 7) __syncthreads();
    }
#undef STAGE_A3
#undef STAGE_B3

    const int col_local = wn * 64 + (l & 15);
    const int rbase = wm * 64 + (l >> 4) * 4;
#pragma unroll
    for (int nf = 0; nf < 4; ++nf) {
        const int n = n0 + col_local + nf * 16;
        const float bs = bias[n];
#pragma unroll
        for (int mf = 0; mf < 4; ++mf) {
            const f32x4 v = acc[mf][nf];
#pragma unroll
            for (int rr = 0; rr < 4; ++rr)
                Cp[(size_t)(m0 + rbase + mf * 16 + rr) * 256 + n] = v[rr] + bs;
        }
    }
}

// ---------------------------------------------------------------------------
// Sampling (v2, R10-proven): block = 256 threads = 2 queries. Phase 1
// (tid<64): softmax + corner indices + pre-multiplied weights -> LDS.
// Phase 2: 128 threads/query, thread=(h=t>>4, d0=(t&15)*2), uint gathers.
// ---------------------------------------------------------------------------
__global__ __launch_bounds__(256)
void sample_kernel(const float* __restrict__ oa,    // [B*NQ, 128] (96 used)
                   const float* __restrict__ ref,   // [B*NQ, 2]
                   const short* __restrict__ vproj, // [B*NH, HW, HD] bf16
                   short* __restrict__ samp)        // [B*NQ, 256] bf16
{
    __shared__ int4   s_idx[2][32];
    __shared__ float4 s_w[2][32];
    const int tid = threadIdx.x;
    const int q0 = blockIdx.x * 2;

    if (tid < 64) {
        const int qq = tid >> 5;
        const int hp = tid & 31;
        const int h = hp >> 2, p = hp & 3;
        const int q = q0 + qq;
        const float logit = oa[(size_t)q * 128 + 64 + h * 4 + p];
        float mx = fmaxf(logit, __shfl_xor(logit, 1));
        mx = fmaxf(mx, __shfl_xor(mx, 2));
        float e = __expf(logit - mx);
        float s = e + __shfl_xor(e, 1);
        s += __shfl_xor(s, 2);
        const float aw = e / s;

        const float ox = oa[(size_t)q * 128 + h * 8 + p * 2 + 0] * (0.1f / (float)W_);
        const float oy = oa[(size_t)q * 128 + h * 8 + p * 2 + 1] * (0.1f / (float)H_);
        const float lx = fminf(fmaxf(ref[(size_t)q * 2 + 0] + ox, 0.f), 1.f);
        const float ly = fminf(fmaxf(ref[(size_t)q * 2 + 1] + oy, 0.f), 1.f);
        const float gx = fminf(fmaxf(lx * (float)W_ - 0.5f, 0.f), (float)(W_ - 1));
        const float gy = fminf(fmaxf(ly * (float)H_ - 0.5f, 0.f), (float)(H_ - 1));
        const float x0f = floorf(gx), y0f = floorf(gy);
        const float fx = gx - x0f, fy = gy - y0f;
        const int x0 = (int)x0f, y0 = (int)y0f;
        const int x1 = min(x0 + 1, W_ - 1), y1 = min(y0 + 1, H_ - 1);
        s_idx[qq][hp] = make_int4((y0 * W_ + x0) * HD_, (y0 * W_ + x1) * HD_,
                                  (y1 * W_ + x0) * HD_, (y1 * W_ + x1) * HD_);
        const float gx1 = 1.f - fx, gy1 = 1.f - fy;
        s_w[qq][hp] = make_float4(aw * gx1 * gy1, aw * fx * gy1,
                                  aw * gx1 * fy,  aw * fx * fy);
    }
    __syncthreads();

    const int qq = tid >> 7;
    const int t = tid & 127;
    const int h = t >> 4;
    const int d0 = (t & 15) * 2;
    const int q = q0 + qq;
    const int b = q >> 13;
    const short* vh = vproj + (size_t)(b * NH_ + h) * (HW_ * HD_) + d0;

    float a0 = 0.f, a1 = 0.f;
#pragma unroll
    for (int p = 0; p < 4; ++p) {
        const int4   ii = s_idx[qq][h * 4 + p];
        const float4 ww = s_w[qq][h * 4 + p];
        unsigned v;
        v = *(const unsigned*)&vh[ii.x];
        a0 = fmaf(ww.x, __uint_as_float(v << 16), a0);
        a1 = fmaf(ww.x, __uint_as_float(v & 0xFFFF0000u), a1);
        v = *(const unsigned*)&vh[ii.y];
        a0 = fmaf(ww.y, __uint_as_float(v << 16), a0);
        a1 = fmaf(ww.y, __uint_as_float(v & 0xFFFF0000u), a1);
        v = *(const unsigned*)&vh[ii.z];
        a0 = fmaf(ww.z, __uint_as_float(v << 16), a0);
        a1 = fmaf(ww.z, __uint_as_float(v & 0xFFFF0000u), a1);
        v = *(const unsigned*)&vh[ii.w];
        a0 = fmaf(ww.w, __uint_as_float(v << 16), a0);
        a1 = fmaf(ww.w, __uint_as_float(v & 0xFFFF0000u), a1);
    }
    const unsigned lo = (unsigned)(unsigned short)f2bf(a0);
    const unsigned hi = (unsigned)(unsigned short)f2bf(a1);
    ((unsigned*)samp)[((size_t)q * 256 + h * HD_ + d0) >> 1] = lo | (hi << 16);
}

// ---------------------------------------------------------------------------
extern "C" void kernel_launch(void* const* d_in, const int* in_sizes, int n_in,
                              void* d_out, int out_size, void* d_ws, size_t ws_size,
                              hipStream_t stream)
{
    const float* query  = (const float*)d_in[0];
    const float* refpt  = (const float*)d_in[1];
    const float* value  = (const float*)d_in[2];
    const float* W_off  = (const float*)d_in[3];
    const float* b_off  = (const float*)d_in[4];
    const float* W_attn = (const float*)d_in[5];
    const float* b_attn = (const float*)d_in[6];
    const float* W_val  = (const float*)d_in[7];
    const float* b_val  = (const float*)d_in[8];
    const float* W_out  = (const float*)d_in[9];
    const float* b_out  = (const float*)d_in[10];
    float* out = (float*)d_out;

    char* ws = (char*)d_ws;
    short* vproj  = (short*)ws;                                   // 32 MiB bf16
    short* samp   = (short*)(ws + (size_t)32 * 1024 * 1024);      // 16 MiB bf16
    float* oa     = (float*)(ws + (size_t)48 * 1024 * 1024);      // 16 MiB f32 [32768][128]
    short* BtVal  = (short*)(ws + (size_t)64 * 1024 * 1024);      // 128 KiB
    short* BtOut  = BtVal + 256 * 256;                            // 128 KiB
    short* BtOA   = BtOut + 256 * 256;                            // 128 KiB (256 rows)
    float* biasOA = (float*)(BtOA + 256 * 256);                   // 1 KiB

    prep_kernel<<<768, 256, 0, stream>>>(W_val, W_out, W_off, W_attn,
                                         b_off, b_attn, BtVal, BtOut, BtOA, biasOA);

    // K1 + K2a: persistent B-stationary GEMM, homogeneous chunk partition
    pgemm<<<256, 512, 0, stream>>>(value, BtVal, b_val, vproj,
                                   query, BtOA, biasOA, oa);

    // K2b: bilinear deformable sampling -> samp (bf16), 2 queries/block
    sample_kernel<<<(B_ * NQ_) / 2, 256, 0, stream>>>(oa, refpt, vproj, samp);

    // K3: out = samp @ W_out + b_out, f32
    gemm_k3<<<512, 256, 0, stream>>>(samp, BtOut, b_out, out);
}